// Round 12
// baseline (20175.243 us; speedup 1.0000x reference)
//
#include <hip/hip_runtime.h>

#define HIDDEN 4096
#define INTER 14336
#define NTOK 8192   // B*S = 4*2048

typedef _Float16 half8 __attribute__((ext_vector_type(8)));
typedef float floatx4 __attribute__((ext_vector_type(4)));

#define AS1C(p) ((const __attribute__((address_space(1))) void*)(p))
#define AS3(p)  ((__attribute__((address_space(3))) void*)(p))
#define SBAR()  __builtin_amdgcn_s_barrier()
#define WAIT_VM0() asm volatile("s_waitcnt vmcnt(0)" ::: "memory")
#define PRIO(x) __builtin_amdgcn_s_setprio(x)
#define MFMA16(A,B,C) __builtin_amdgcn_mfma_f32_16x16x32_f16(A,B,C,0,0,0)

// ---------------- conversion kernels (R4 versions) ----------------

__global__ void cvt_w_kernel(const int* __restrict__ src, _Float16* __restrict__ dst, long n) {
    long i0 = ((long)blockIdx.x * blockDim.x + threadIdx.x) * 8;
    long stride = (long)gridDim.x * blockDim.x * 8;
    for (long i = i0; i < n; i += stride) {
        int4 a = *(const int4*)(src + i);
        int4 b = *(const int4*)(src + i + 4);
        half8 h;
        h[0] = (_Float16)a.x; h[1] = (_Float16)a.y; h[2] = (_Float16)a.z; h[3] = (_Float16)a.w;
        h[4] = (_Float16)b.x; h[5] = (_Float16)b.y; h[6] = (_Float16)b.z; h[7] = (_Float16)b.w;
        *(half8*)(dst + i) = h;
    }
}

__global__ void cvt_x_kernel(const float* __restrict__ src, _Float16* __restrict__ dst, long n) {
    long i0 = ((long)blockIdx.x * blockDim.x + threadIdx.x) * 8;
    long stride = (long)gridDim.x * blockDim.x * 8;
    for (long i = i0; i < n; i += stride) {
        float4 a = *(const float4*)(src + i);
        float4 b = *(const float4*)(src + i + 4);
        half8 h;
        h[0] = (_Float16)a.x; h[1] = (_Float16)a.y; h[2] = (_Float16)a.z; h[3] = (_Float16)a.w;
        h[4] = (_Float16)b.x; h[5] = (_Float16)b.y; h[6] = (_Float16)b.z; h[7] = (_Float16)b.w;
        *(half8*)(dst + i) = h;
    }
}

// ---------------- fused gate+up (R4 4-phase, SINGLE-buffered, 2 blocks/CU) ----------------
// BM=256, BN=128, BK=64, 512 thr (8 waves, 2M x 4N).
// LDS 64KB: A 32KB + Bg 16KB + Bu 16KB (single buffer) -> 2 blocks/CU.
// Cross-block overlap (m114): independent blocks' LDS-read / MFMA / staging-stall
// phases anti-align and fill each other's pipe idle time — the overlap that
// R4-R11's intra-block schedules could not create at 1 block/CU.
// Phases: P0 g(m0-3) [ds aLo+bg], P1 g(m4-7) [ds aHi], P2 u(m0-3) [ds bu],
//         P3 u(m4-7) [buffer fully read by end-P2 barrier -> stage t+1 here;
//                     vmcnt(0); SBAR]. Stall is covered by the sibling block.
// Co-resident blocks are bn-adjacent (same bm) -> share the A panel in L2.

__global__ __launch_bounds__(512, 4) void gateup_kernel(
        const _Float16* __restrict__ Aptr, const _Float16* __restrict__ Bgp,
        const _Float16* __restrict__ Bup, const float* __restrict__ gsc,
        const float* __restrict__ usc, _Float16* __restrict__ H)
{
    constexpr int KDIM = HIDDEN;
    constexpr int NT = KDIM / 64;      // 64
    constexpr int NBN = INTER / 128;   // 112
    __shared__ _Float16 sA[256 * 64];
    __shared__ _Float16 sG[128 * 64];
    __shared__ _Float16 sU[128 * 64];

    const int tid  = threadIdx.x;
    const int lane = tid & 63;
    const int wid  = tid >> 6;
    const int wr   = wid >> 2;   // 0..1
    const int wc   = wid & 3;    // 0..3

    const int nwg = gridDim.x;
    const int bid = blockIdx.x;
    const int swz = (bid & 7) * (nwg >> 3) + (bid >> 3);
    const int bm = swz / NBN;
    const int bn = swz % NBN;

    // staging addresses (T2: pre-swizzled global source slot)
    const int srow  = tid >> 3;                  // 0..63
    const int sslot = (tid & 7) ^ (srow & 7);
    const _Float16* gA = Aptr + ((long)bm * 256 + srow) * KDIM + sslot * 8;
    const _Float16* gG = Bgp + ((long)bn * 128 + srow) * KDIM + sslot * 8;
    const _Float16* gU = Bup + ((long)bn * 128 + srow) * KDIM + sslot * 8;

    auto stageAll = [&](int t) {   // full tile t: 8 loads/thread into the single buffer
        _Float16* dA = &sA[tid * 8];
        _Float16* dG = &sG[tid * 8];
        _Float16* dU = &sU[tid * 8];
        const _Float16* sa = gA + (long)t * 64;
        const _Float16* sg = gG + (long)t * 64;
        const _Float16* su = gU + (long)t * 64;
#pragma unroll
        for (int p = 0; p < 4; ++p)
            __builtin_amdgcn_global_load_lds(AS1C(sa + (long)p * 64 * KDIM), AS3(dA + p * 4096), 16, 0, 0);
#pragma unroll
        for (int p = 0; p < 2; ++p) {
            __builtin_amdgcn_global_load_lds(AS1C(sg + (long)p * 64 * KDIM), AS3(dG + p * 4096), 16, 0, 0);
            __builtin_amdgcn_global_load_lds(AS1C(su + (long)p * 64 * KDIM), AS3(dU + p * 4096), 16, 0, 0);
        }
    };

    // ds_read fragment offsets (elements); row&7 == lane&7 for all frags
    const int arow = wr * 128 + (lane & 15);
    const int brow = wc * 32  + (lane & 15);
    const int sl0 = ((lane >> 4) ^ (lane & 7)) * 8;
    const int sl1 = ((4 + (lane >> 4)) ^ (lane & 7)) * 8;
    const int aof0 = arow * 64 + sl0, aof1 = arow * 64 + sl1;
    const int bof0 = brow * 64 + sl0, bof1 = brow * 64 + sl1;

    floatx4 ag[8][2] = {};
    floatx4 au[8][2] = {};
    half8 a[8][2], bg[2][2], bu[2][2];

    // prologue: tile 0
    stageAll(0);
    WAIT_VM0();
    SBAR();

    for (int t = 0; t < NT; ++t) {
        // ---- P0: ds aLo + bg; MFMA g m0-3 ----
#pragma unroll
        for (int m = 0; m < 4; ++m) {
            a[m][0] = *(const half8*)(sA + aof0 + m * 1024);
            a[m][1] = *(const half8*)(sA + aof1 + m * 1024);
        }
#pragma unroll
        for (int n = 0; n < 2; ++n) {
            bg[n][0] = *(const half8*)(sG + bof0 + n * 1024);
            bg[n][1] = *(const half8*)(sG + bof1 + n * 1024);
        }
        SBAR();
        PRIO(1);
#pragma unroll
        for (int m = 0; m < 4; ++m)
#pragma unroll
            for (int n = 0; n < 2; ++n) {
                ag[m][n] = MFMA16(a[m][0], bg[n][0], ag[m][n]);
                ag[m][n] = MFMA16(a[m][1], bg[n][1], ag[m][n]);
            }
        PRIO(0);
        SBAR();

        // ---- P1: ds aHi; MFMA g m4-7 ----
#pragma unroll
        for (int m = 4; m < 8; ++m) {
            a[m][0] = *(const half8*)(sA + aof0 + m * 1024);
            a[m][1] = *(const half8*)(sA + aof1 + m * 1024);
        }
        SBAR();
        PRIO(1);
#pragma unroll
        for (int m = 4; m < 8; ++m)
#pragma unroll
            for (int n = 0; n < 2; ++n) {
                ag[m][n] = MFMA16(a[m][0], bg[n][0], ag[m][n]);
                ag[m][n] = MFMA16(a[m][1], bg[n][1], ag[m][n]);
            }
        PRIO(0);
        SBAR();

        // ---- P2: ds bu; MFMA u m0-3 ----
#pragma unroll
        for (int n = 0; n < 2; ++n) {
            bu[n][0] = *(const half8*)(sU + bof0 + n * 1024);
            bu[n][1] = *(const half8*)(sU + bof1 + n * 1024);
        }
        SBAR();
        PRIO(1);
#pragma unroll
        for (int m = 0; m < 4; ++m)
#pragma unroll
            for (int n = 0; n < 2; ++n) {
                au[m][n] = MFMA16(a[m][0], bu[n][0], au[m][n]);
                au[m][n] = MFMA16(a[m][1], bu[n][1], au[m][n]);
            }
        PRIO(0);
        SBAR();   // after this barrier the buffer is fully consumed

        // ---- P3: stage t+1 into the (fully-read) buffer; MFMA u m4-7; drain ----
        if (t + 1 < NT) stageAll(t + 1);
        PRIO(1);
#pragma unroll
        for (int m = 4; m < 8; ++m)
#pragma unroll
            for (int n = 0; n < 2; ++n) {
                au[m][n] = MFMA16(a[m][0], bu[n][0], au[m][n]);
                au[m][n] = MFMA16(a[m][1], bu[n][1], au[m][n]);
            }
        PRIO(0);
        if (t + 1 < NT) { WAIT_VM0(); }   // stall covered by the sibling block
        SBAR();
    }

    // ---- epilogue: h = silu(g*gs) * (u*us), fp16 ----
    const int orow = bm * 256 + wr * 128 + ((lane >> 4) * 4);
    const int ocol = bn * 128 + wc * 32 + (lane & 15);
#pragma unroll
    for (int n = 0; n < 2; ++n) {
        const int col = ocol + n * 16;
        const float gs = gsc[col];
        const float us = usc[col];
#pragma unroll
        for (int m = 0; m < 8; ++m) {
            const int row = orow + m * 16;
#pragma unroll
            for (int q = 0; q < 4; ++q) {
                const float g = ag[m][n][q] * gs;
                const float u = au[m][n][q] * us;
                H[(long)(row + q) * INTER + col] = (_Float16)(g / (1.0f + __expf(-g)) * u);
            }
        }
    }
}

// ---------------- down GEMM (R4 4-phase 256x256, SINGLE-buffered, 2 blocks/CU) ----------------

__global__ __launch_bounds__(512, 4) void down_kernel(
        const _Float16* __restrict__ Aptr, const _Float16* __restrict__ Bptr,
        const float* __restrict__ dsc, float* __restrict__ out)
{
    constexpr int KDIM = INTER;
    constexpr int NT = KDIM / 64;     // 224
    constexpr int NBN = HIDDEN / 256; // 16
    __shared__ _Float16 sA[256 * 64];
    __shared__ _Float16 sB[256 * 64];

    const int tid  = threadIdx.x;
    const int lane = tid & 63;
    const int wid  = tid >> 6;
    const int wr   = wid >> 2;
    const int wc   = wid & 3;

    const int nwg = gridDim.x;
    const int bid = blockIdx.x;
    const int swz = (bid & 7) * (nwg >> 3) + (bid >> 3);
    const int bm = swz / NBN;
    const int bn = swz % NBN;

    const int srow  = tid >> 3;
    const int sslot = (tid & 7) ^ (srow & 7);
    const _Float16* gA = Aptr + ((long)bm * 256 + srow) * KDIM + sslot * 8;
    const _Float16* gB = Bptr + ((long)bn * 256 + srow) * KDIM + sslot * 8;

    auto stageAll = [&](int t) {   // 8 loads/thread
        _Float16* dA = &sA[tid * 8];
        _Float16* dB = &sB[tid * 8];
        const _Float16* sa = gA + (long)t * 64;
        const _Float16* sb = gB + (long)t * 64;
#pragma unroll
        for (int p = 0; p < 4; ++p) {
            __builtin_amdgcn_global_load_lds(AS1C(sa + (long)p * 64 * KDIM), AS3(dA + p * 4096), 16, 0, 0);
            __builtin_amdgcn_global_load_lds(AS1C(sb + (long)p * 64 * KDIM), AS3(dB + p * 4096), 16, 0, 0);
        }
    };

    const int arow = wr * 128 + (lane & 15);
    const int brow = wc * 64  + (lane & 15);
    const int sl0 = ((lane >> 4) ^ (lane & 7)) * 8;
    const int sl1 = ((4 + (lane >> 4)) ^ (lane & 7)) * 8;
    const int aof0 = arow * 64 + sl0, aof1 = arow * 64 + sl1;
    const int bof0 = brow * 64 + sl0, bof1 = brow * 64 + sl1;

    floatx4 acc[8][4] = {};
    half8 a[8][2], b[4][2];

    stageAll(0);
    WAIT_VM0();
    SBAR();

    for (int t = 0; t < NT; ++t) {
        // ---- P0: ds aLo + b01; MFMA m0-3 x n0-1 ----
#pragma unroll
        for (int m = 0; m < 4; ++m) {
            a[m][0] = *(const half8*)(sA + aof0 + m * 1024);
            a[m][1] = *(const half8*)(sA + aof1 + m * 1024);
        }
#pragma unroll
        for (int n = 0; n < 2; ++n) {
            b[n][0] = *(const half8*)(sB + bof0 + n * 1024);
            b[n][1] = *(const half8*)(sB + bof1 + n * 1024);
        }
        SBAR();
        PRIO(1);
#pragma unroll
        for (int m = 0; m < 4; ++m)
#pragma unroll
            for (int n = 0; n < 2; ++n) {
                acc[m][n] = MFMA16(a[m][0], b[n][0], acc[m][n]);
                acc[m][n] = MFMA16(a[m][1], b[n][1], acc[m][n]);
            }
        PRIO(0);
        SBAR();

        // ---- P1: ds b23; MFMA m0-3 x n2-3 ----
#pragma unroll
        for (int n = 2; n < 4; ++n) {
            b[n][0] = *(const half8*)(sB + bof0 + n * 1024);
            b[n][1] = *(const half8*)(sB + bof1 + n * 1024);
        }
        SBAR();
        PRIO(1);
#pragma unroll
        for (int m = 0; m < 4; ++m)
#pragma unroll
            for (int n = 2; n < 4; ++n) {
                acc[m][n] = MFMA16(a[m][0], b[n][0], acc[m][n]);
                acc[m][n] = MFMA16(a[m][1], b[n][1], acc[m][n]);
            }
        PRIO(0);
        SBAR();

        // ---- P2: ds aHi; MFMA m4-7 x n2-3 ----
#pragma unroll
        for (int m = 4; m < 8; ++m) {
            a[m][0] = *(const half8*)(sA + aof0 + m * 1024);
            a[m][1] = *(const half8*)(sA + aof1 + m * 1024);
        }
        SBAR();
        PRIO(1);
#pragma unroll
        for (int m = 4; m < 8; ++m)
#pragma unroll
            for (int n = 2; n < 4; ++n) {
                acc[m][n] = MFMA16(a[m][0], b[n][0], acc[m][n]);
                acc[m][n] = MFMA16(a[m][1], b[n][1], acc[m][n]);
            }
        PRIO(0);
        SBAR();   // buffer fully consumed

        // ---- P3: stage t+1; MFMA m4-7 x n0-1; drain ----
        if (t + 1 < NT) stageAll(t + 1);
        PRIO(1);
#pragma unroll
        for (int m = 4; m < 8; ++m)
#pragma unroll
            for (int n = 0; n < 2; ++n) {
                acc[m][n] = MFMA16(a[m][0], b[n][0], acc[m][n]);
                acc[m][n] = MFMA16(a[m][1], b[n][1], acc[m][n]);
            }
        PRIO(0);
        if (t + 1 < NT) { WAIT_VM0(); }
        SBAR();
    }

    const int orow = bm * 256 + wr * 128 + ((lane >> 4) * 4);
    const int ocol = bn * 256 + wc * 64 + (lane & 15);
#pragma unroll
    for (int n = 0; n < 4; ++n) {
        const int col = ocol + n * 16;
        const float sc = dsc[col];
#pragma unroll
        for (int m = 0; m < 8; ++m) {
            const int row = orow + m * 16;
#pragma unroll
            for (int q = 0; q < 4; ++q)
                out[(long)(row + q) * HIDDEN + col] = acc[m][n][q] * sc;
        }
    }
}

// ---------------- launch ----------------

extern "C" void kernel_launch(void* const* d_in, const int* in_sizes, int n_in,
                              void* d_out, int out_size, void* d_ws, size_t ws_size,
                              hipStream_t stream) {
    const float* x   = (const float*)d_in[0];
    const int*   gw  = (const int*)d_in[1];
    const float* gsc = (const float*)d_in[2];
    const int*   uw  = (const int*)d_in[3];
    const float* usc = (const float*)d_in[4];
    const int*   dw  = (const int*)d_in[5];
    const float* dsc = (const float*)d_in[6];
    float* out = (float*)d_out;

    char* ws = (char*)d_ws;
    _Float16* x16  = (_Float16*)(ws);                    //  64 MiB
    _Float16* wg16 = (_Float16*)(ws + 67108864ll);       // 112 MiB
    _Float16* wu16 = (_Float16*)(ws + 184549376ll);      // 112 MiB
    _Float16* wd16 = (_Float16*)(ws + 301989888ll);      // 112 MiB
    _Float16* h16  = (_Float16*)(ws + 419430400ll);      // 224 MiB

    cvt_x_kernel<<<4096, 256, 0, stream>>>(x,  x16,  (long)NTOK * HIDDEN);
    cvt_w_kernel<<<4096, 256, 0, stream>>>(gw, wg16, (long)INTER * HIDDEN);
    cvt_w_kernel<<<4096, 256, 0, stream>>>(uw, wu16, (long)INTER * HIDDEN);
    cvt_w_kernel<<<4096, 256, 0, stream>>>(dw, wd16, (long)HIDDEN * INTER);

    // fused gate+up+SwiGLU: [8192 x 14336], h fp16
    gateup_kernel<<<(NTOK / 256) * (INTER / 128), 512, 0, stream>>>(
        x16, wg16, wu16, gsc, usc, h16);
    // down: [8192 x 4096] = H * Wd^T, fp32 out
    down_kernel<<<(NTOK / 256) * (HIDDEN / 256), 512, 0, stream>>>(
        h16, wd16, dsc, out);
}